// Round 11
// baseline (134.796 us; speedup 1.0000x reference)
//
#include <hip/hip_runtime.h>

#ifndef __has_builtin
#define __has_builtin(x) 0
#endif
#if __has_builtin(__builtin_amdgcn_fdot2)
#define HAVE_FDOT2 1
#else
#define HAVE_FDOT2 0
#endif

typedef _Float16 f16;
typedef _Float16 f16x2 __attribute__((ext_vector_type(2)));
typedef _Float16 f16x8 __attribute__((ext_vector_type(8)));
typedef float    f32x4 __attribute__((ext_vector_type(4)));
typedef float    f32x2 __attribute__((ext_vector_type(2)));
typedef unsigned int u32x4 __attribute__((ext_vector_type(4)));

#define Bn 16
#define Cn 256
#define Hn 48
#define Wn 64
#define NDISP 21
#define SLAB 32768                      // bytes per (b,row) slab of in2, f16
#define WS_NEED ((size_t)Bn * Hn * SLAB)   // 25.2 MB

// ============================================================================
// Conversion kernel (in2 only), VERIFIED R5-R10: f32 [b][c][row][w] -> f16 ws
// slabs in MFMA-B-FRAGMENT order:
//   slab(b,row) offset = kc*8192 + par*4096 + ni*2048 + kk*1024 + g*256 + nl*16 + j*2
//   holds in2[b][c = kc*64 + kk*32 + g*8 + j][row][w = 2*(ni*16+nl) + par]
// ============================================================================
__global__ __launch_bounds__(256) void convert_kernel(const float* __restrict__ in2,
                                                      char* __restrict__ ws)
{
    int i = blockIdx.x;                         // 0..767
    int b = i / Hn, row = i % Hn;
    char* dslab = ws + (size_t)i * SLAB;
    int t  = threadIdx.x;
    int nl = t & 15, g = (t >> 4) & 3, kk = (t >> 6) & 1, ni = (t >> 7) & 1;
    int wq = ni * 16 + nl;                      // w' 0..31
    const float* srcb = in2 + ((size_t)b * Cn * Hn + row) * Wn;
    char* dbase = dslab + ni * 2048 + kk * 1024 + g * 256 + nl * 16;
    #pragma unroll
    for (int kc = 0; kc < 4; ++kc) {
        union { f16 h[8]; u32x4 u; } e0, e1;
        #pragma unroll
        for (int j = 0; j < 8; ++j) {
            int c = kc * 64 + kk * 32 + g * 8 + j;
            f32x2 v = *(const f32x2*)&srcb[(size_t)c * Hn * Wn + 2 * wq];
            e0.h[j] = (f16)v.x;                 // even w  (par 0)
            e1.h[j] = (f16)v.y;                 // odd  w  (par 1)
        }
        *(u32x4*)(dbase + kc * 8192)        = e0.u;
        *(u32x4*)(dbase + kc * 8192 + 4096) = e1.u;
    }
}

// ============================================================================
// Main kernel V11: block = (b,h), 1024 threads = 16 waves = 8 dy-slots x 2
// m-halves. NO barriers, NO global_load_lds, NO asm waitcnt: per k8, the
// wave loads 4 x f16x8 B-fragments (both parities x both ni) straight from
// the fragment-ordered ws into registers (coalesced 16B/lane) and feeds 8
// MFMAs. Compiler pipelines the unrolled straight-line gram; 4 waves/SIMD
// hide the remaining latency. Private LDS bounce (672 f32/wave) merges both
// parities so gather emits full f32x4 coalesced stores.
// ============================================================================
template<int NG>
__device__ void corr_wave(const char* __restrict__ wsb,
                          float* __restrict__ outb,
                          const f16x8 (&af)[2][8],
                          float* bp,
                          int h, int dylo, int slot, int half, int l)
{
    const int nl  = l & 15;
    const int g   = l >> 4;
    const int l16 = l * 16;

    const char* gs[NG];
    #pragma unroll
    for (int gi = 0; gi < NG; ++gi) {
        int dy = dylo + slot + 8 * gi;
        int r  = h + 2 * dy - 20;               // in [0,48) by construction
        gs[gi] = wsb + (size_t)r * SLAB;
    }

    #pragma unroll
    for (int gi = 0; gi < NG; ++gi) {
        const int dy = dylo + slot + 8 * gi;

        f32x4 acc[2][2];                        // [par][ni]
        acc[0][0] = acc[0][1] = acc[1][0] = acc[1][1] = (f32x4){0.f, 0.f, 0.f, 0.f};

        #pragma unroll
        for (int k8 = 0; k8 < 8; ++k8) {
            const char* kb = gs[gi] + (k8 >> 1) * 8192 + (k8 & 1) * 1024 + l16;
            f16x8 b00 = *(const f16x8*)(kb);                // par0, ni0
            f16x8 b01 = *(const f16x8*)(kb + 2048);         // par0, ni1
            f16x8 b10 = *(const f16x8*)(kb + 4096);         // par1, ni0
            f16x8 b11 = *(const f16x8*)(kb + 6144);         // par1, ni1
            acc[0][0] = __builtin_amdgcn_mfma_f32_16x16x32_f16(af[0][k8], b00, acc[0][0], 0, 0, 0);
            acc[0][1] = __builtin_amdgcn_mfma_f32_16x16x32_f16(af[0][k8], b01, acc[0][1], 0, 0, 0);
            acc[1][0] = __builtin_amdgcn_mfma_f32_16x16x32_f16(af[1][k8], b10, acc[1][0], 0, 0, 0);
            acc[1][1] = __builtin_amdgcn_mfma_f32_16x16x32_f16(af[1][k8], b11, acc[1][1], 0, 0, 0);
        }

        // ---- extraction via private bounce [21 dx][32 w-local], XOR-swizzled.
        // D layout (verified): col n = ni*16+nl, row m = half*16 + 4g + rr.
        // o = n - m = dx-10; w_local = 2*(4g+rr) + par.
        #pragma unroll
        for (int it = 0; it < 11; ++it) {
            int j = it * 64 + l;
            if (j < 672) bp[j] = 0.f;
        }
        asm volatile("" ::: "memory");
        #pragma unroll
        for (int p2 = 0; p2 < 2; ++p2)
            #pragma unroll
            for (int ni = 0; ni < 2; ++ni)
                #pragma unroll
                for (int rr = 0; rr < 4; ++rr) {
                    int o = nl + 16 * ni - 16 * half - 4 * g - rr;   // dx - 10
                    if (o >= -10 && o <= 10) {
                        int dx = o + 10;
                        int wl = 2 * (4 * g + rr) + p2;              // 0..31
                        bp[dx * 32 + (wl ^ ((dx & 7) << 2))] = acc[p2][ni][rr];
                    }
                }
        asm volatile("" ::: "memory");
        // ---- gather + coalesced f32x4 stores: 168 positions (21 dx x 8 quads)
        #pragma unroll
        for (int jt = 0; jt < 3; ++jt) {
            int pos = jt * 64 + l;
            if (pos < 168) {
                int dx = pos >> 3;
                int q  = pos & 7;
                int sw = (dx & 7) << 2;
                f32x4 v;
                v.x = bp[dx * 32 + ((4 * q)     ^ sw)];
                v.y = bp[dx * 32 + ((4 * q + 1) ^ sw)];
                v.z = bp[dx * 32 + ((4 * q + 2) ^ sw)];
                v.w = bp[dx * 32 + ((4 * q + 3) ^ sw)];
                v = v * (1.0f / 256.0f);
                *(f32x4*)&outb[((size_t)(dy * NDISP + dx) * Hn + h) * Wn
                               + half * 32 + 4 * q] = v;
            }
        }
        asm volatile("" ::: "memory");          // bounce reused by next gram
    }
}

__global__ __launch_bounds__(1024, 4) void corr_mfma(const float* __restrict__ in1,
                                                     const char* __restrict__ ws,
                                                     float* __restrict__ out)
{
    __shared__ float bounce[16][672];           // 43 KB, per-wave private

    const int tid  = threadIdx.x;
    const int wv   = tid >> 6;                  // 0..15
    const int l    = tid & 63;
    const int nl   = l & 15;
    const int g    = l >> 4;
    const int slot = wv >> 1;                   // dy slot 0..7
    const int half = wv & 1;                    // m-half 0..1

    // XCD-affinity mapping (verified bijective): xcd = bid&7 owns b in
    // {2*xcd, 2*xcd+1} -> per-XCD ws slice 3.15 MB = L2-resident.
    int bid = blockIdx.x;
    int rr8 = bid >> 3;                         // 0..95
    int b   = 2 * (bid & 7) + (rr8 >= Hn ? 1 : 0);
    int h   = rr8 % Hn;

    const float* in1b = in1 + (size_t)b * Cn * Hn * Wn;
    const char*  wsb  = ws  + (size_t)b * Hn * SLAB;
    float* outb = out + (size_t)b * (NDISP * NDISP) * Hn * Wn;

    int dylo = (h < 20) ? ((21 - h) >> 1) : 0;
    int dyhi = min(NDISP, ((67 - h) >> 1) + 1);
    int V    = dyhi - dylo;                     // 11..21 (every slot has >=1)

    // ---- zero invalid-dy planes (all 16 waves cooperate; coalesced f32x4) ----
    {
        int nz = NDISP - V;
        f32x4 z = {0.f, 0.f, 0.f, 0.f};
        for (int j = tid; j < nz * NDISP * 16; j += 1024) {
            int zi  = j / (NDISP * 16);
            int rem = j - zi * (NDISP * 16);
            int dy  = (zi < dylo) ? zi : (dyhi + (zi - dylo));
            int dx  = rem >> 4;
            int wq  = rem & 15;
            *(f32x4*)&outb[((size_t)(dy * NDISP + dx) * Hn + h) * Wn + wq * 4] = z;
        }
    }

    // ---- A-fragments (VERIFIED contract, mi fixed = half): af[par][k8]
    //      elem j = f16(in1[c=k8*32+g*8+j][h][w=2*(half*16+nl)+par]) ----
    f16x8 af[2][8];
    {
        const int w2 = 2 * (half * 16 + nl);
        #pragma unroll
        for (int k8 = 0; k8 < 8; ++k8)
            #pragma unroll
            for (int j = 0; j < 8; ++j) {
                int c = k8 * 32 + g * 8 + j;
                f32x2 v = *(const f32x2*)&in1b[((size_t)c * Hn + h) * Wn + w2];
                af[0][k8][j] = (f16)v.x;
                af[1][k8][j] = (f16)v.y;
            }
    }

    int ng = (V - slot + 7) >> 3;               // 1..3
    float* bp = &bounce[wv][0];

    if (ng >= 3)      corr_wave<3>(wsb, outb, af, bp, h, dylo, slot, half, l);
    else if (ng == 2) corr_wave<2>(wsb, outb, af, bp, h, dylo, slot, half, l);
    else              corr_wave<1>(wsb, outb, af, bp, h, dylo, slot, half, l);
}

// ============================================================================
// Fallback (round-1 kernel, known-good) if ws_size is too small.
// ============================================================================
#define BDIM 384
#define C2T  8
#define NCHUNK 16
#define JJN  56
#define IN1_DW (2*128*32)
#define IN2_DW (128*JJN + 64)

__device__ __forceinline__ unsigned int packh2(float a, float b) {
    union { f16x2 h; unsigned int u; } u;
    u.h.x = (_Float16)a; u.h.y = (_Float16)b;
    return u.u;
}
__device__ __forceinline__ float dot2(unsigned int a, unsigned int b, float c) {
    union { unsigned int u; f16x2 h; } ua, ub;
    ua.u = a; ub.u = b;
#if HAVE_FDOT2
    return __builtin_amdgcn_fdot2(ua.h, ub.h, c, false);
#else
    return c + (float)ua.h.x * (float)ub.h.x + (float)ua.h.y * (float)ub.h.y;
#endif
}
__device__ __forceinline__ int in2row(int m) { return m * JJN + (((m >> 3) & 1) << 2); }

__global__ __launch_bounds__(BDIM, 3) void corr_fallback(
    const float* __restrict__ in1, const float* __restrict__ in2,
    float* __restrict__ out)
{
    __shared__ __align__(16) unsigned int s_in1[IN1_DW];
    __shared__ __align__(16) unsigned int s_in2[IN2_DW];
    const int tid = threadIdx.x;
    int bid = blockIdx.x;
    int sw  = (bid & 7) * 96 + (bid >> 3);
    const int b = sw / Hn;
    const int h = sw - b * Hn;
    int dylo = (h < 20) ? ((21 - h) >> 1) : 0;
    int dyhi = min(NDISP - 1, (67 - h) >> 1) + 1;
    const int V = dyhi - dylo;
    const int wg   = tid & 15;
    const int p    = wg & 1;
    const int widx = (wg >> 1) << 2;
    const int t2   = tid >> 4;
    const int dxg  = t2 % 3;
    const int slot = t2 / 3;
    const int dxb  = dxg << 3;
    const float* in1b = in1 + (size_t)b * Cn * Hn * Wn;
    const float* in2b = in2 + (size_t)b * Cn * Hn * Wn;
    float* outb = out + (size_t)b * (NDISP * NDISP) * Hn * Wn;
    {
        int nz = NDISP - V;
        for (int j = tid; j < nz * NDISP * Wn; j += BDIM) {
            int zi  = j / (NDISP * Wn);
            int rem = j - zi * (NDISP * Wn);
            int dy  = (zi < dylo) ? zi : (dyhi + (zi - dylo));
            int dx  = rem >> 6;
            int w   = rem & 63;
            outb[((size_t)(dy * NDISP + dx) * Hn + h) * Wn + w] = 0.0f;
        }
    }
    for (int i = tid; i < 64 * 128; i += BDIM) {
        int w  = i & 63;
        int c2 = i >> 6;
        float f0 = in1b[((size_t)(2 * c2)     * Hn + h) * Wn + w];
        float f1 = in1b[((size_t)(2 * c2 + 1) * Hn + h) * Wn + w];
        int pp = w & 1, wq = w >> 1;
        s_in1[(pp * 128 + c2) * 32 + wq] = packh2(f0, f1);
    }
    const int nR = (V + 7) >> 3;
    for (int round = 0; round < nR; ++round) {
        const int dy0   = dylo + (round << 3);
        const int mydy  = dy0 + slot;
        const bool valid = (mydy < dyhi);
        float acc[4][8];
        #pragma unroll
        for (int i = 0; i < 4; ++i)
            #pragma unroll
            for (int j = 0; j < 8; ++j) acc[i][j] = 0.0f;
        for (int ch = 0; ch < NCHUNK; ++ch) {
            const int c2b = ch * C2T;
            __syncthreads();
            for (int i = tid; i < 8 * 2 * C2T * 112 / 2; i += BDIM) {
                int jj2 = i % 112;
                int t   = i / 112;
                int pp  = jj2 & 1;
                int jj  = jj2 >> 1;
                int c2o = t % C2T;
                int sl  = t / C2T;
                int dy  = dy0 + sl;
                if (dy >= dyhi) continue;
                int w2  = jj2 - 20;
                unsigned int val = 0;
                if (w2 >= 0 && w2 < Wn) {
                    int rr = h + 2 * dy - 20;
                    int c = 2 * (c2b + c2o);
                    const float* srcp = &in2b[((size_t)c * Hn + rr) * Wn + w2];
                    val = packh2(srcp[0], srcp[Hn * Wn]);
                }
                s_in2[in2row((sl * 2 + pp) * C2T + c2o) + jj] = val;
            }
            __syncthreads();
            if (valid) {
                const int base1 = (p * 128 + c2b) * 32 + widx;
                #pragma unroll
                for (int c2o = 0; c2o < C2T; ++c2o) {
                    u32x4 a4 = *(const u32x4*)&s_in1[base1 + c2o * 32];
                    const unsigned int* vr =
                        &s_in2[in2row((slot * 2 + p) * C2T + c2o) + widx + dxb];
                    u32x4 v0 = *(const u32x4*)(vr);
                    u32x4 v1 = *(const u32x4*)(vr + 4);
                    u32x4 v2 = *(const u32x4*)(vr + 8);
                    unsigned int av[4]  = {a4.x, a4.y, a4.z, a4.w};
                    unsigned int vv[12] = {v0.x, v0.y, v0.z, v0.w,
                                           v1.x, v1.y, v1.z, v1.w,
                                           v2.x, v2.y, v2.z, v2.w};
                    #pragma unroll
                    for (int wi = 0; wi < 4; ++wi)
                        #pragma unroll
                        for (int di = 0; di < 8; ++di)
                            acc[wi][di] = dot2(av[wi], vv[wi + di], acc[wi][di]);
                }
            }
        }
        float* s_out = (float*)s_in2;
        for (int half = 0; half < 2; ++half) {
            __syncthreads();
            if (((slot >> 2) == half) && valid) {
                #pragma unroll
                for (int wi = 0; wi < 4; ++wi)
                    #pragma unroll
                    for (int di = 0; di < 8; ++di) {
                        int dx = dxb + di;
                        if (dx < NDISP) {
                            int w = p + ((widx + wi) << 1);
                            s_out[(((slot & 3) * NDISP + dx) << 6) + w] =
                                acc[wi][di] * (1.0f / 256.0f);
                        }
                    }
            }
            __syncthreads();
            int dyb = dy0 + (half << 2);
            for (int j = tid; j < 4 * NDISP * Wn; j += BDIM) {
                int s  = j / (NDISP * Wn);
                int dy = dyb + s;
                if (dy < dyhi) {
                    int rem = j - s * (NDISP * Wn);
                    int dx  = rem >> 6;
                    int w   = rem & 63;
                    outb[((size_t)(dy * NDISP + dx) * Hn + h) * Wn + w] = s_out[j];
                }
            }
        }
    }
}

extern "C" void kernel_launch(void* const* d_in, const int* in_sizes, int n_in,
                              void* d_out, int out_size, void* d_ws, size_t ws_size,
                              hipStream_t stream) {
    (void)in_sizes; (void)n_in; (void)out_size;
    const float* in1 = (const float*)d_in[0];
    const float* in2 = (const float*)d_in[1];
    float* out = (float*)d_out;
    if (ws_size >= WS_NEED) {
        convert_kernel<<<dim3(Bn * Hn), dim3(256), 0, stream>>>(in2, (char*)d_ws);
        corr_mfma<<<dim3(Bn * Hn), dim3(1024), 0, stream>>>(in1, (const char*)d_ws, out);
    } else {
        corr_fallback<<<dim3(Bn * Hn), dim3(BDIM), 0, stream>>>(in1, in2, out);
    }
}

// Round 12
// 79.775 us; speedup vs baseline: 1.6897x; 1.6897x over previous
//
#include <hip/hip_runtime.h>

#ifndef __has_builtin
#define __has_builtin(x) 0
#endif
#if __has_builtin(__builtin_amdgcn_fdot2)
#define HAVE_FDOT2 1
#else
#define HAVE_FDOT2 0
#endif

typedef _Float16 f16;
typedef _Float16 f16x2 __attribute__((ext_vector_type(2)));
typedef _Float16 f16x8 __attribute__((ext_vector_type(8)));
typedef float    f32x4 __attribute__((ext_vector_type(4)));
typedef float    f32x2 __attribute__((ext_vector_type(2)));
typedef unsigned int u32x4 __attribute__((ext_vector_type(4)));

#define Bn 16
#define Cn 256
#define Hn 48
#define Wn 64
#define NDISP 21
#define SLAB 32768                      // bytes per (b,row) slab of in2, f16
#define WS_NEED ((size_t)Bn * Hn * SLAB)   // 25.2 MB

// ============================================================================
// Conversion kernel (in2 only), VERIFIED R5-R11: f32 [b][c][row][w] -> f16 ws
// slabs in MFMA-B-FRAGMENT order:
//   slab(b,row) offset = kc*8192 + par*4096 + ni*2048 + kk*1024 + g*256 + nl*16 + j*2
//   holds in2[b][c = kc*64 + kk*32 + g*8 + j][row][w = 2*(ni*16+nl) + par]
// ============================================================================
__global__ __launch_bounds__(256) void convert_kernel(const float* __restrict__ in2,
                                                      char* __restrict__ ws)
{
    int i = blockIdx.x;                         // 0..767
    int b = i / Hn, row = i % Hn;
    char* dslab = ws + (size_t)i * SLAB;
    int t  = threadIdx.x;
    int nl = t & 15, g = (t >> 4) & 3, kk = (t >> 6) & 1, ni = (t >> 7) & 1;
    int wq = ni * 16 + nl;                      // w' 0..31
    const float* srcb = in2 + ((size_t)b * Cn * Hn + row) * Wn;
    char* dbase = dslab + ni * 2048 + kk * 1024 + g * 256 + nl * 16;
    #pragma unroll
    for (int kc = 0; kc < 4; ++kc) {
        union { f16 h[8]; u32x4 u; } e0, e1;
        #pragma unroll
        for (int j = 0; j < 8; ++j) {
            int c = kc * 64 + kk * 32 + g * 8 + j;
            f32x2 v = *(const f32x2*)&srcb[(size_t)c * Hn * Wn + 2 * wq];
            e0.h[j] = (f16)v.x;                 // even w  (par 0)
            e1.h[j] = (f16)v.y;                 // odd  w  (par 1)
        }
        *(u32x4*)(dbase + kc * 8192)        = e0.u;
        *(u32x4*)(dbase + kc * 8192 + 4096) = e1.u;
    }
}

// ============================================================================
// Main kernel V12 = V11's PASSING per-wave math, re-geometried to 512-thread
// blocks (V11's 1024-thread blocks forced a 128-VGPR launch cap -> 64+spill,
// WRITE 177 MB). Grid 1536 = (b,h,sub); block = 8 waves = 4 dy-slots x 2
// m-halves; slot = 4*sub + (wv>>1). No barriers, no global_load_lds, no asm
// waitcnt: per k8 the wave loads 4 x f16x8 B-frags (both parities x both ni)
// straight from fragment-ordered ws into registers and feeds 4 MFMAs; the
// compiler pipelines; ~4 waves/SIMD hide latency. Private LDS bounce merges
// parities so stores are full coalesced f32x4.
// ============================================================================
template<int NG>
__device__ void corr_wave(const char* __restrict__ wsb,
                          float* __restrict__ outb,
                          const f16x8 (&af)[2][8],
                          float* bp,
                          int h, int dylo, int slot, int half, int l)
{
    const int nl  = l & 15;
    const int g   = l >> 4;
    const int l16 = l * 16;

    const char* gs[NG];
    #pragma unroll
    for (int gi = 0; gi < NG; ++gi) {
        int dy = dylo + slot + 8 * gi;
        int r  = h + 2 * dy - 20;               // in [0,48) by construction
        gs[gi] = wsb + (size_t)r * SLAB;
    }

    #pragma unroll
    for (int gi = 0; gi < NG; ++gi) {
        const int dy = dylo + slot + 8 * gi;

        f32x4 acc[2][2];                        // [par][ni]
        acc[0][0] = acc[0][1] = acc[1][0] = acc[1][1] = (f32x4){0.f, 0.f, 0.f, 0.f};

        #pragma unroll
        for (int k8 = 0; k8 < 8; ++k8) {
            const char* kb = gs[gi] + (k8 >> 1) * 8192 + (k8 & 1) * 1024 + l16;
            f16x8 b00 = *(const f16x8*)(kb);                // par0, ni0
            f16x8 b01 = *(const f16x8*)(kb + 2048);         // par0, ni1
            f16x8 b10 = *(const f16x8*)(kb + 4096);         // par1, ni0
            f16x8 b11 = *(const f16x8*)(kb + 6144);         // par1, ni1
            acc[0][0] = __builtin_amdgcn_mfma_f32_16x16x32_f16(af[0][k8], b00, acc[0][0], 0, 0, 0);
            acc[0][1] = __builtin_amdgcn_mfma_f32_16x16x32_f16(af[0][k8], b01, acc[0][1], 0, 0, 0);
            acc[1][0] = __builtin_amdgcn_mfma_f32_16x16x32_f16(af[1][k8], b10, acc[1][0], 0, 0, 0);
            acc[1][1] = __builtin_amdgcn_mfma_f32_16x16x32_f16(af[1][k8], b11, acc[1][1], 0, 0, 0);
        }

        // ---- extraction via private bounce [21 dx][32 w-local], XOR-swizzled.
        // D layout (verified): col n = ni*16+nl, row m = half*16 + 4g + rr.
        // o = n - m = dx-10; w_local = 2*(4g+rr) + par.
        #pragma unroll
        for (int it = 0; it < 11; ++it) {
            int j = it * 64 + l;
            if (j < 672) bp[j] = 0.f;
        }
        asm volatile("" ::: "memory");
        #pragma unroll
        for (int p2 = 0; p2 < 2; ++p2)
            #pragma unroll
            for (int ni = 0; ni < 2; ++ni)
                #pragma unroll
                for (int rr = 0; rr < 4; ++rr) {
                    int o = nl + 16 * ni - 16 * half - 4 * g - rr;   // dx - 10
                    if (o >= -10 && o <= 10) {
                        int dx = o + 10;
                        int wl = 2 * (4 * g + rr) + p2;              // 0..31
                        bp[dx * 32 + (wl ^ ((dx & 7) << 2))] = acc[p2][ni][rr];
                    }
                }
        asm volatile("" ::: "memory");
        // ---- gather + coalesced f32x4 stores: 168 positions (21 dx x 8 quads)
        #pragma unroll
        for (int jt = 0; jt < 3; ++jt) {
            int pos = jt * 64 + l;
            if (pos < 168) {
                int dx = pos >> 3;
                int q  = pos & 7;
                int sw = (dx & 7) << 2;
                f32x4 v;
                v.x = bp[dx * 32 + ((4 * q)     ^ sw)];
                v.y = bp[dx * 32 + ((4 * q + 1) ^ sw)];
                v.z = bp[dx * 32 + ((4 * q + 2) ^ sw)];
                v.w = bp[dx * 32 + ((4 * q + 3) ^ sw)];
                v = v * (1.0f / 256.0f);
                *(f32x4*)&outb[((size_t)(dy * NDISP + dx) * Hn + h) * Wn
                               + half * 32 + 4 * q] = v;
            }
        }
        asm volatile("" ::: "memory");          // bounce reused by next gram
    }
}

__global__ __launch_bounds__(512, 2) void corr_mfma(const float* __restrict__ in1,
                                                    const char* __restrict__ ws,
                                                    float* __restrict__ out)
{
    __shared__ float bounce[8][672];            // 21.5 KB, per-wave private

    const int tid  = threadIdx.x;
    const int wv   = tid >> 6;                  // 0..7
    const int l    = tid & 63;
    const int nl   = l & 15;
    const int g    = l >> 4;
    const int half = wv & 1;                    // m-half 0..1

    // XCD-affine bijective mapping over 1536 = 8 xcd * 2 b * 48 h * 2 sub:
    // xcd owns b in {2*xcd, 2*xcd+1} -> per-XCD ws slice 3.15 MB (L2-fit).
    int bid = blockIdx.x;
    int rr  = bid >> 3;                         // 0..191
    int b   = 2 * (bid & 7) + (rr >= 96 ? 1 : 0);
    int q   = (rr >= 96) ? (rr - 96) : rr;      // 0..95
    int h   = q >> 1;
    int sub = q & 1;
    const int slot = 4 * sub + (wv >> 1);       // dy slot 0..7

    const float* in1b = in1 + (size_t)b * Cn * Hn * Wn;
    const char*  wsb  = ws  + (size_t)b * Hn * SLAB;
    float* outb = out + (size_t)b * (NDISP * NDISP) * Hn * Wn;

    int dylo = (h < 20) ? ((21 - h) >> 1) : 0;
    int dyhi = min(NDISP, ((67 - h) >> 1) + 1);
    int V    = dyhi - dylo;                     // 11..21 (every slot has >=1)

    // ---- zero invalid-dy planes, split across the two sibling blocks ----
    {
        int nz = NDISP - V;
        f32x4 z = {0.f, 0.f, 0.f, 0.f};
        for (int zi = sub; zi < nz; zi += 2) {
            int dy = (zi < dylo) ? zi : (dyhi + (zi - dylo));
            for (int j = tid; j < NDISP * 16; j += 512) {
                int dx = j >> 4;
                int wq = j & 15;
                *(f32x4*)&outb[((size_t)(dy * NDISP + dx) * Hn + h) * Wn + wq * 4] = z;
            }
        }
    }

    // ---- A-fragments (VERIFIED contract, mi fixed = half): af[par][k8]
    //      elem j = f16(in1[c=k8*32+g*8+j][h][w=2*(half*16+nl)+par]) ----
    f16x8 af[2][8];
    {
        const int w2 = 2 * (half * 16 + nl);
        #pragma unroll
        for (int k8 = 0; k8 < 8; ++k8)
            #pragma unroll
            for (int j = 0; j < 8; ++j) {
                int c = k8 * 32 + g * 8 + j;
                f32x2 v = *(const f32x2*)&in1b[((size_t)c * Hn + h) * Wn + w2];
                af[0][k8][j] = (f16)v.x;
                af[1][k8][j] = (f16)v.y;
            }
    }

    int ng = (V - slot + 7) >> 3;               // 1..3 (V>=11 > slot max 7)
    float* bp = &bounce[wv][0];

    if (ng >= 3)      corr_wave<3>(wsb, outb, af, bp, h, dylo, slot, half, l);
    else if (ng == 2) corr_wave<2>(wsb, outb, af, bp, h, dylo, slot, half, l);
    else              corr_wave<1>(wsb, outb, af, bp, h, dylo, slot, half, l);
}

// ============================================================================
// Fallback (round-1 kernel, known-good) if ws_size is too small.
// ============================================================================
#define BDIM 384
#define C2T  8
#define NCHUNK 16
#define JJN  56
#define IN1_DW (2*128*32)
#define IN2_DW (128*JJN + 64)

__device__ __forceinline__ unsigned int packh2(float a, float b) {
    union { f16x2 h; unsigned int u; } u;
    u.h.x = (_Float16)a; u.h.y = (_Float16)b;
    return u.u;
}
__device__ __forceinline__ float dot2(unsigned int a, unsigned int b, float c) {
    union { unsigned int u; f16x2 h; } ua, ub;
    ua.u = a; ub.u = b;
#if HAVE_FDOT2
    return __builtin_amdgcn_fdot2(ua.h, ub.h, c, false);
#else
    return c + (float)ua.h.x * (float)ub.h.x + (float)ua.h.y * (float)ub.h.y;
#endif
}
__device__ __forceinline__ int in2row(int m) { return m * JJN + (((m >> 3) & 1) << 2); }

__global__ __launch_bounds__(BDIM, 3) void corr_fallback(
    const float* __restrict__ in1, const float* __restrict__ in2,
    float* __restrict__ out)
{
    __shared__ __align__(16) unsigned int s_in1[IN1_DW];
    __shared__ __align__(16) unsigned int s_in2[IN2_DW];
    const int tid = threadIdx.x;
    int bid = blockIdx.x;
    int sw  = (bid & 7) * 96 + (bid >> 3);
    const int b = sw / Hn;
    const int h = sw - b * Hn;
    int dylo = (h < 20) ? ((21 - h) >> 1) : 0;
    int dyhi = min(NDISP - 1, (67 - h) >> 1) + 1;
    const int V = dyhi - dylo;
    const int wg   = tid & 15;
    const int p    = wg & 1;
    const int widx = (wg >> 1) << 2;
    const int t2   = tid >> 4;
    const int dxg  = t2 % 3;
    const int slot = t2 / 3;
    const int dxb  = dxg << 3;
    const float* in1b = in1 + (size_t)b * Cn * Hn * Wn;
    const float* in2b = in2 + (size_t)b * Cn * Hn * Wn;
    float* outb = out + (size_t)b * (NDISP * NDISP) * Hn * Wn;
    {
        int nz = NDISP - V;
        for (int j = tid; j < nz * NDISP * Wn; j += BDIM) {
            int zi  = j / (NDISP * Wn);
            int rem = j - zi * (NDISP * Wn);
            int dy  = (zi < dylo) ? zi : (dyhi + (zi - dylo));
            int dx  = rem >> 6;
            int w   = rem & 63;
            outb[((size_t)(dy * NDISP + dx) * Hn + h) * Wn + w] = 0.0f;
        }
    }
    for (int i = tid; i < 64 * 128; i += BDIM) {
        int w  = i & 63;
        int c2 = i >> 6;
        float f0 = in1b[((size_t)(2 * c2)     * Hn + h) * Wn + w];
        float f1 = in1b[((size_t)(2 * c2 + 1) * Hn + h) * Wn + w];
        int pp = w & 1, wq = w >> 1;
        s_in1[(pp * 128 + c2) * 32 + wq] = packh2(f0, f1);
    }
    const int nR = (V + 7) >> 3;
    for (int round = 0; round < nR; ++round) {
        const int dy0   = dylo + (round << 3);
        const int mydy  = dy0 + slot;
        const bool valid = (mydy < dyhi);
        float acc[4][8];
        #pragma unroll
        for (int i = 0; i < 4; ++i)
            #pragma unroll
            for (int j = 0; j < 8; ++j) acc[i][j] = 0.0f;
        for (int ch = 0; ch < NCHUNK; ++ch) {
            const int c2b = ch * C2T;
            __syncthreads();
            for (int i = tid; i < 8 * 2 * C2T * 112 / 2; i += BDIM) {
                int jj2 = i % 112;
                int t   = i / 112;
                int pp  = jj2 & 1;
                int jj  = jj2 >> 1;
                int c2o = t % C2T;
                int sl  = t / C2T;
                int dy  = dy0 + sl;
                if (dy >= dyhi) continue;
                int w2  = jj2 - 20;
                unsigned int val = 0;
                if (w2 >= 0 && w2 < Wn) {
                    int rr = h + 2 * dy - 20;
                    int c = 2 * (c2b + c2o);
                    const float* srcp = &in2b[((size_t)c * Hn + rr) * Wn + w2];
                    val = packh2(srcp[0], srcp[Hn * Wn]);
                }
                s_in2[in2row((sl * 2 + pp) * C2T + c2o) + jj] = val;
            }
            __syncthreads();
            if (valid) {
                const int base1 = (p * 128 + c2b) * 32 + widx;
                #pragma unroll
                for (int c2o = 0; c2o < C2T; ++c2o) {
                    u32x4 a4 = *(const u32x4*)&s_in1[base1 + c2o * 32];
                    const unsigned int* vr =
                        &s_in2[in2row((slot * 2 + p) * C2T + c2o) + widx + dxb];
                    u32x4 v0 = *(const u32x4*)(vr);
                    u32x4 v1 = *(const u32x4*)(vr + 4);
                    u32x4 v2 = *(const u32x4*)(vr + 8);
                    unsigned int av[4]  = {a4.x, a4.y, a4.z, a4.w};
                    unsigned int vv[12] = {v0.x, v0.y, v0.z, v0.w,
                                           v1.x, v1.y, v1.z, v1.w,
                                           v2.x, v2.y, v2.z, v2.w};
                    #pragma unroll
                    for (int wi = 0; wi < 4; ++wi)
                        #pragma unroll
                        for (int di = 0; di < 8; ++di)
                            acc[wi][di] = dot2(av[wi], vv[wi + di], acc[wi][di]);
                }
            }
        }
        float* s_out = (float*)s_in2;
        for (int half = 0; half < 2; ++half) {
            __syncthreads();
            if (((slot >> 2) == half) && valid) {
                #pragma unroll
                for (int wi = 0; wi < 4; ++wi)
                    #pragma unroll
                    for (int di = 0; di < 8; ++di) {
                        int dx = dxb + di;
                        if (dx < NDISP) {
                            int w = p + ((widx + wi) << 1);
                            s_out[(((slot & 3) * NDISP + dx) << 6) + w] =
                                acc[wi][di] * (1.0f / 256.0f);
                        }
                    }
            }
            __syncthreads();
            int dyb = dy0 + (half << 2);
            for (int j = tid; j < 4 * NDISP * Wn; j += BDIM) {
                int s  = j / (NDISP * Wn);
                int dy = dyb + s;
                if (dy < dyhi) {
                    int rem = j - s * (NDISP * Wn);
                    int dx  = rem >> 6;
                    int w   = rem & 63;
                    outb[((size_t)(dy * NDISP + dx) * Hn + h) * Wn + w] = s_out[j];
                }
            }
        }
    }
}

extern "C" void kernel_launch(void* const* d_in, const int* in_sizes, int n_in,
                              void* d_out, int out_size, void* d_ws, size_t ws_size,
                              hipStream_t stream) {
    (void)in_sizes; (void)n_in; (void)out_size;
    const float* in1 = (const float*)d_in[0];
    const float* in2 = (const float*)d_in[1];
    float* out = (float*)d_out;
    if (ws_size >= WS_NEED) {
        convert_kernel<<<dim3(Bn * Hn), dim3(256), 0, stream>>>(in2, (char*)d_ws);
        corr_mfma<<<dim3(2 * Bn * Hn), dim3(512), 0, stream>>>(in1, (const char*)d_ws, out);
    } else {
        corr_fallback<<<dim3(Bn * Hn), dim3(BDIM), 0, stream>>>(in1, in2, out);
    }
}